// Round 2
// baseline (173.009 us; speedup 1.0000x reference)
//
#include <hip/hip_runtime.h>
#include <math.h>

// Problem dims fixed by setup_inputs()
#define B 2
#define T 8
#define M 1024
#define NB 2048
#define N_RES 128
#define TILE 32
#define NTILES (M / TILE)                      // 32
#define NTPAIRS (NTILES * (NTILES + 1) / 2)    // 528
#define PAIR_BLOCKS (B * NTPAIRS)              // 1056
#define BOND_BLOCKS ((B * T * NB) / 256)       // 128
#define STRUCT_BLOCKS (B * T)                  // 16
#define NBLK (PAIR_BLOCKS + BOND_BLOCKS + STRUCT_BLOCKS)  // 1200

// workspace float offsets
#define WS_SCORE  0
#define WS_PAIRS  1
#define WS_STRUCT 2
#define WS_BONDN  3
#define WS_BONDD  4
#define WS_DONE   5               // used as int
#define WS_FLEXS  8               // B*N_RES
#define WS_FLEXC  (8 + B * N_RES)
#define WS_TOTAL  (8 + 2 * B * N_RES)   // 520 floats

// rational sigmoid-sum constants: f(u) = u*Q'(u)/Q(u), Q = prod_k (1 + c_k u),
// c_k = e^{th_k}, th = {0.5, 1, 2, 4}.  score = 0.25 * f(e^{-diff}).
#define C_E1 66.35420923125896f
#define C_E2 678.6088038500627f
#define C_E3 2039.5821756957330f
#define C_E4 1808.0424144560632f
#define C_P0 C_E1
#define C_P1 1357.2176077001254f
#define C_P2 6118.7465270871990f
#define C_P3 7232.1696578242530f

__device__ inline float block_reduce(float v, float* smem) {
    int lane = threadIdx.x & 63, wid = threadIdx.x >> 6;
#pragma unroll
    for (int off = 32; off > 0; off >>= 1) v += __shfl_down(v, off, 64);
    __syncthreads();
    if (lane == 0) smem[wid] = v;
    __syncthreads();
    float r = 0.f;
    if (threadIdx.x == 0) {
        for (int i = 0; i < 4; i++) r += smem[i];
    }
    return r;   // valid on thread 0 only
}

__global__ __launch_bounds__(256) void k_fused(
        const float* __restrict__ xp, const float* __restrict__ xg,
        const float* __restrict__ sigma, const float* __restrict__ blen,
        const int* __restrict__ cond, const int* __restrict__ amask,
        const int* __restrict__ omask, const int* __restrict__ mtype,
        const int* __restrict__ resid, const int* __restrict__ bidx,
        const int* __restrict__ bmask, float* __restrict__ ws,
        float* __restrict__ out) {
    __shared__ float red[8], red2[8];
    __shared__ float sI[T][TILE][8];     // px,py,pz,gx,gy,gz,pad,pad
    __shared__ float sJ[T][TILE][8];
    __shared__ float s_valI[TILE], s_valJ[TILE];
    __shared__ int   s_resI[TILE], s_resJ[TILE];
    __shared__ int   s_last;

    const int tid = threadIdx.x;
    const int blk = blockIdx.x;

    if (blk < PAIR_BLOCKS) {
        // ---------------- fused lDDT + flexibility over pair tiles ----------------
        int bb = blk / NTPAIRS;
        int p  = blk % NTPAIRS;
        int ti = 0, rem = p;
        while (rem >= NTILES - ti) { rem -= NTILES - ti; ti++; }
        int tj = ti + rem;

        // frame weights from cond (cheap, uniform)
        float fw[T], tg[T];
        float cb = 0.f;
#pragma unroll
        for (int t = 0; t < T; t++) {
            tg[t] = (cond[bb * T + t] == 0) ? 1.f : 0.f;
            cb += tg[t];
        }
        float inv = 1.f / fmaxf(cb, 1.f);
        float S0 = cb * inv;
#pragma unroll
        for (int t = 0; t < T; t++) fw[t] = tg[t] * inv;

        // stage both tiles: thread -> (t, a)
        {
            int t = tid >> 5, a = tid & 31;
            size_t base = ((size_t)(bb * T + t)) * M * 3;
            const float* P = xp + base;
            const float* G = xg + base;
            int ia = (ti * TILE + a) * 3, ja = (tj * TILE + a) * 3;
            sI[t][a][0] = P[ia + 0]; sI[t][a][1] = P[ia + 1]; sI[t][a][2] = P[ia + 2];
            sI[t][a][3] = G[ia + 0]; sI[t][a][4] = G[ia + 1]; sI[t][a][5] = G[ia + 2];
            sJ[t][a][0] = P[ja + 0]; sJ[t][a][1] = P[ja + 1]; sJ[t][a][2] = P[ja + 2];
            sJ[t][a][3] = G[ja + 0]; sJ[t][a][4] = G[ja + 1]; sJ[t][a][5] = G[ja + 2];
        }
        if (tid < TILE) {
            int i = ti * TILE + tid, j = tj * TILE + tid;
            s_valI[tid] = (amask[bb * M + i] && omask[bb * M + i]) ? 1.f : 0.f;
            s_valJ[tid] = (amask[bb * M + j] && omask[bb * M + j]) ? 1.f : 0.f;
            s_resI[tid] = resid[bb * M + i];
            s_resJ[tid] = resid[bb * M + j];
        }
        __syncthreads();

        // i-side coords into registers (one-time LDS reads)
        const int ii = tid & 31;
        float ipx[T], ipy[T], ipz[T], igx[T], igy[T], igz[T];
#pragma unroll
        for (int t = 0; t < T; t++) {
            float4 a4 = *(const float4*)&sI[t][ii][0];
            float4 b4 = *(const float4*)&sI[t][ii][4];
            ipx[t] = a4.x; ipy[t] = a4.y; ipz[t] = a4.z;
            igx[t] = a4.w; igy[t] = b4.x; igz[t] = b4.y;
        }
        const float vI = s_valI[ii];
        const int   rI = s_resI[ii];
        const int   gi = ti * TILE + ii;
        const int jbase = (tid >> 5) * 4;

        float score_sum = 0.f, cnt_sum = 0.f;
#pragma unroll
        for (int l = 0; l < 4; l++) {
            int jj = jbase + l;
            int gj = tj * TILE + jj;
            float w = (gi < gj) ? vI * s_valJ[jj] : 0.f;   // strict upper triangle + valid
            float S1p = 0.f, S2p = 0.f, S1g = 0.f, S2g = 0.f;
            float isc = 0.f, icnt = 0.f;
#pragma unroll
            for (int t = 0; t < T; t++) {
                float4 a4 = *(const float4*)&sJ[t][jj][0];   // broadcast in half-wave
                float4 b4 = *(const float4*)&sJ[t][jj][4];
                float dx = ipx[t] - a4.x, dy = ipy[t] - a4.y, dz = ipz[t] - a4.z;
                float d2p = fmaxf(fmaf(dx, dx, fmaf(dy, dy, dz * dz)), 1e-12f);
                float dp = __builtin_amdgcn_sqrtf(d2p);
                dx = igx[t] - a4.w; dy = igy[t] - b4.x; dz = igz[t] - b4.y;
                float d2g = fmaxf(fmaf(dx, dx, fmaf(dy, dy, dz * dz)), 1e-12f);
                float dg = __builtin_amdgcn_sqrtf(d2g);
                S1p = fmaf(fw[t], dp, S1p);  S2p = fmaf(fw[t], d2p, S2p);
                S1g = fmaf(fw[t], dg, S1g);  S2g = fmaf(fw[t], d2g, S2g);
                float diff = fabsf(dp - dg);
                float u = __expf(-diff);
                float Pn = fmaf(u, fmaf(u, fmaf(u, C_P3, C_P2), C_P1), C_P0);
                float Qd = fmaf(u, fmaf(u, fmaf(u, fmaf(u, C_E4, C_E3), C_E2), C_E1), 1.f);
                float s4 = u * Pn * __builtin_amdgcn_rcpf(Qd);
                float mk = (dg < 15.f) ? tg[t] : 0.f;       // dmask (predicated)
                isc = fmaf(mk, s4, isc);
                icnt += mk;
            }
            score_sum = fmaf(w * 0.25f, isc, score_sum);
            cnt_sum = fmaf(w, icnt, cnt_sum);
            if (w > 0.f && rI == s_resJ[jj]) {
                // sum_t fw (d-m)^2 = S2 - S1^2 (2 - S0)
                float varp = fmaxf(fmaf(-S1p * S1p, 2.f - S0, S2p), 0.f);
                float varg = fmaxf(fmaf(-S1g * S1g, 2.f - S0, S2g), 0.f);
                float ds = __builtin_amdgcn_sqrtf(varp + 1e-8f)
                         - __builtin_amdgcn_sqrtf(varg + 1e-8f);
                int seg = bb * N_RES + rI;
                atomicAdd(ws + WS_FLEXS + seg, ds * ds);
                atomicAdd(ws + WS_FLEXC + seg, 1.f);
            }
        }
        float sc = block_reduce(score_sum, red);
        float ct = block_reduce(cnt_sum, red2);
        if (tid == 0) {
            atomicAdd(ws + WS_SCORE, 2.f * sc);   // symmetric full-matrix count
            atomicAdd(ws + WS_PAIRS, 2.f * ct);
        }
    } else if (blk < PAIR_BLOCKS + BOND_BLOCKS) {
        // ---------------- bond loss ----------------
        int gid = (blk - PAIR_BLOCKS) * 256 + tid;   // < B*T*NB
        int bb = gid / (T * NB);
        int r  = gid % (T * NB);
        int t = r / NB, k = r % NB;
        float w = ((cond[bb * T + t] == 0) && bmask[bb * NB + k]) ? 1.f : 0.f;
        int i = bidx[(bb * NB + k) * 2 + 0];
        int j = bidx[(bb * NB + k) * 2 + 1];
        const float* base = xp + (size_t)(bb * T + t) * M * 3;
        float dx = base[i * 3 + 0] - base[j * 3 + 0];
        float dy = base[i * 3 + 1] - base[j * 3 + 1];
        float dz = base[i * 3 + 2] - base[j * 3 + 2];
        float len = __builtin_amdgcn_sqrtf(fmaf(dx, dx, fmaf(dy, dy, dz * dz)) + 1e-12f);
        float d = len - blen[bb * NB + k];
        float n = block_reduce(w * d * d, red);
        float dn = block_reduce(w, red2);
        if (tid == 0) {
            atomicAdd(ws + WS_BONDN, n);
            atomicAdd(ws + WS_BONDD, dn);
        }
    } else {
        // ---------------- structure loss ----------------
        int bt = blk - PAIR_BLOCKS - BOND_BLOCKS;    // 0..B*T-1
        int bb = bt / T, t = bt % T;
        const float molw[4] = {1.f, 5.f, 5.f, 10.f};
        const float* p = xp + (size_t)(bb * T + t) * M * 3;
        const float* g = xg + (size_t)(bb * T + t) * M * 3;
        float lw = 0.f, lv = 0.f;
        for (int m = tid; m < M; m += 256) {
            float v = (amask[bb * M + m] && omask[bb * M + m]) ? 1.f : 0.f;
            lv += v;
            float dx = p[m * 3 + 0] - g[m * 3 + 0];
            float dy = p[m * 3 + 1] - g[m * 3 + 1];
            float dz = p[m * 3 + 2] - g[m * 3 + 2];
            lw += fmaf(dx, dx, fmaf(dy, dy, dz * dz)) * v * molw[mtype[bb * M + m] & 3];
        }
        float tot = block_reduce(lw, red);
        float nv  = block_reduce(lv, red2);
        if (tid == 0) {
            float per_frame = tot / fmaxf(nv, 1.f);
            float s = sigma[bb * T + t];
            float targ = (cond[bb * T + t] == 0) ? 1.f : 0.f;
            float den = s * 16.0f + 1e-8f;
            float edm = (s * s + 256.0f) / (den * den) * targ;
            atomicAdd(ws + WS_STRUCT, edm * per_frame);
        }
    }

    // ---------------- last-block final combine ----------------
    __threadfence();
    __syncthreads();
    if (tid == 0) {
        int old = __hip_atomic_fetch_add((int*)ws + WS_DONE, 1,
                                         __ATOMIC_ACQ_REL, __HIP_MEMORY_SCOPE_AGENT);
        s_last = (old == NBLK - 1) ? 1 : 0;
    }
    __syncthreads();
    if (s_last) {
        float ls = 0.f, ln = 0.f;
        for (int seg = tid; seg < B * N_RES; seg += 256) {
            float c = __hip_atomic_load(ws + WS_FLEXC + seg,
                                        __ATOMIC_RELAXED, __HIP_MEMORY_SCOPE_AGENT);
            if (c > 0.f) {
                float s = __hip_atomic_load(ws + WS_FLEXS + seg,
                                            __ATOMIC_RELAXED, __HIP_MEMORY_SCOPE_AGENT);
                ls += s / c;
                ln += 1.f;
            }
        }
        float ssum = block_reduce(ls, red);
        float nsum = block_reduce(ln, red2);
        if (tid == 0) {
            float tc = 0.f;
            for (int i = 0; i < B * T; i++) tc += (cond[i] == 0) ? 1.f : 0.f;
            float l_struct = __hip_atomic_load(ws + WS_STRUCT, __ATOMIC_RELAXED,
                                               __HIP_MEMORY_SCOPE_AGENT) / fmaxf(tc, 1.f);
            float bn = __hip_atomic_load(ws + WS_BONDN, __ATOMIC_RELAXED,
                                         __HIP_MEMORY_SCOPE_AGENT);
            float bd = __hip_atomic_load(ws + WS_BONDD, __ATOMIC_RELAXED,
                                         __HIP_MEMORY_SCOPE_AGENT);
            float sc = __hip_atomic_load(ws + WS_SCORE, __ATOMIC_RELAXED,
                                         __HIP_MEMORY_SCOPE_AGENT);
            float pr = __hip_atomic_load(ws + WS_PAIRS, __ATOMIC_RELAXED,
                                         __HIP_MEMORY_SCOPE_AGENT);
            float l_bond = bn / fmaxf(bd, 1.f);
            float l_lddt = 1.f - sc / fmaxf(pr, 1.f);
            float l_local = ssum / fmaxf(nsum, 1.f);
            out[0] = l_struct + l_bond + l_lddt + 4.0f * l_local;
        }
    }
}

extern "C" void kernel_launch(void* const* d_in, const int* in_sizes, int n_in,
                              void* d_out, int out_size, void* d_ws, size_t ws_size,
                              hipStream_t stream) {
    const float* xp    = (const float*)d_in[0];   // (B,T,M,3)
    const float* xg    = (const float*)d_in[1];   // (B,T,M,3)
    const float* sigma = (const float*)d_in[2];   // (B,T)
    const float* blen  = (const float*)d_in[3];   // (B,NB)
    const int*   cond  = (const int*)d_in[4];     // (B,T) bool->int32
    const int*   amask = (const int*)d_in[5];     // (B,M)
    const int*   omask = (const int*)d_in[6];     // (B,M)
    const int*   mtype = (const int*)d_in[7];     // (B,M)
    const int*   resid = (const int*)d_in[8];     // (B,M)
    const int*   bidx  = (const int*)d_in[9];     // (B,NB,2)
    const int*   bmask = (const int*)d_in[10];    // (B,NB)
    float* out = (float*)d_out;
    float* ws  = (float*)d_ws;

    hipMemsetAsync(ws, 0, WS_TOTAL * sizeof(float), stream);
    k_fused<<<NBLK, 256, 0, stream>>>(xp, xg, sigma, blen, cond, amask, omask,
                                      mtype, resid, bidx, bmask, ws, out);
}

// Round 3
// 117.839 us; speedup vs baseline: 1.4682x; 1.4682x over previous
//
#include <hip/hip_runtime.h>
#include <math.h>

// Problem dims fixed by setup_inputs()
#define B 2
#define T 8
#define M 1024
#define NB 2048
#define N_RES 128
#define TILE 32
#define NTILES (M / TILE)                      // 32
#define NTPAIRS (NTILES * (NTILES + 1) / 2)    // 528
#define PAIR_BLOCKS (B * NTPAIRS)              // 1056
#define BOND_BLOCKS ((B * T * NB) / 256)       // 128
#define STRUCT_BLOCKS (B * T)                  // 16
#define NBLK (PAIR_BLOCKS + BOND_BLOCKS + STRUCT_BLOCKS)  // 1200

// workspace float offsets
#define WS_SCORE  0
#define WS_PAIRS  1
#define WS_STRUCT 2
#define WS_BONDN  3
#define WS_BONDD  4
#define WS_FLEXS  8               // B*N_RES
#define WS_FLEXC  (8 + B * N_RES)
#define WS_TOTAL  (8 + 2 * B * N_RES)   // 520 floats

// rational sigmoid-sum: sum_k sigmoid(th_k - diff) = u*Q'(u)/Q(u), u=e^{-diff},
// Q = prod_k (1 + c_k u), c_k = e^{th_k}, th = {0.5, 1, 2, 4}.
#define C_E1 66.35420923125896f
#define C_E2 678.6088038500627f
#define C_E3 2039.5821756957330f
#define C_E4 1808.0424144560632f
#define C_P0 C_E1
#define C_P1 1357.2176077001254f
#define C_P2 6118.7465270871990f
#define C_P3 7232.1696578242530f

__device__ inline float block_reduce(float v, float* smem) {
    int lane = threadIdx.x & 63, wid = threadIdx.x >> 6;
#pragma unroll
    for (int off = 32; off > 0; off >>= 1) v += __shfl_down(v, off, 64);
    __syncthreads();
    if (lane == 0) smem[wid] = v;
    __syncthreads();
    float r = 0.f;
    if (threadIdx.x == 0) {
        for (int i = 0; i < 4; i++) r += smem[i];
    }
    return r;   // valid on thread 0 only
}

// main kernel: pair blocks [0,1056), bond [1056,1184), struct [1184,1200).
// NO fence / done-flag: the kernel boundary syncs before k_final.
__global__ __launch_bounds__(256) void k_main(
        const float* __restrict__ xp, const float* __restrict__ xg,
        const float* __restrict__ sigma, const float* __restrict__ blen,
        const int* __restrict__ cond, const int* __restrict__ amask,
        const int* __restrict__ omask, const int* __restrict__ mtype,
        const int* __restrict__ resid, const int* __restrict__ bidx,
        const int* __restrict__ bmask, float* __restrict__ ws) {
    __shared__ float red[8], red2[8];
    __shared__ float sI[T][TILE][6];     // stride-6: 2-way bank alias (free)
    __shared__ float sJ[T][TILE][8];     // stride-8: read as broadcast float4
    __shared__ float s_valJ[TILE];
    __shared__ int   s_resJ[TILE];

    const int tid = threadIdx.x;
    const int blk = blockIdx.x;

    if (blk < PAIR_BLOCKS) {
        // ---------------- fused lDDT + flexibility over pair tiles ----------------
        int bb = blk / NTPAIRS;
        int p  = blk % NTPAIRS;
        int ti = 0, rem = p;
        while (rem >= NTILES - ti) { rem -= NTILES - ti; ti++; }
        int tj = ti + rem;

        // frame weights from cond (uniform scalar work)
        float fw[T], tg[T];
        float cb = 0.f;
#pragma unroll
        for (int t = 0; t < T; t++) {
            tg[t] = (cond[bb * T + t] == 0) ? 1.f : 0.f;
            cb += tg[t];
        }
        float inv = 1.f / fmaxf(cb, 1.f);
        float S0 = cb * inv;
#pragma unroll
        for (int t = 0; t < T; t++) fw[t] = tg[t] * inv;

        // stage both tiles: thread -> (t, a)
        {
            int t = tid >> 5, a = tid & 31;
            size_t base = ((size_t)(bb * T + t)) * M * 3;
            const float* P = xp + base;
            const float* G = xg + base;
            int ia = (ti * TILE + a) * 3, ja = (tj * TILE + a) * 3;
            sI[t][a][0] = P[ia + 0]; sI[t][a][1] = P[ia + 1]; sI[t][a][2] = P[ia + 2];
            sI[t][a][3] = G[ia + 0]; sI[t][a][4] = G[ia + 1]; sI[t][a][5] = G[ia + 2];
            sJ[t][a][0] = P[ja + 0]; sJ[t][a][1] = P[ja + 1]; sJ[t][a][2] = P[ja + 2];
            sJ[t][a][3] = G[ja + 0]; sJ[t][a][4] = G[ja + 1]; sJ[t][a][5] = G[ja + 2];
        }
        if (tid < TILE) {
            int j = tj * TILE + tid;
            s_valJ[tid] = (amask[bb * M + j] && omask[bb * M + j]) ? 1.f : 0.f;
            s_resJ[tid] = resid[bb * M + j];
        }
        __syncthreads();

        // i-side coords into registers: stride-6 scalar reads, 2-way alias (free)
        const int ii = tid & 31;
        float ipx[T], ipy[T], ipz[T], igx[T], igy[T], igz[T];
#pragma unroll
        for (int t = 0; t < T; t++) {
            ipx[t] = sI[t][ii][0]; ipy[t] = sI[t][ii][1]; ipz[t] = sI[t][ii][2];
            igx[t] = sI[t][ii][3]; igy[t] = sI[t][ii][4]; igz[t] = sI[t][ii][5];
        }
        const int   gi = ti * TILE + ii;
        const float vI = (amask[bb * M + gi] && omask[bb * M + gi]) ? 1.f : 0.f;
        const int   rI = resid[bb * M + gi];
        const int jbase = (tid >> 5) * 4;

        float score_sum = 0.f, cnt_sum = 0.f;
#pragma unroll
        for (int l = 0; l < 4; l++) {
            int jj = jbase + l;
            int gj = tj * TILE + jj;
            float w = (gi < gj) ? vI * s_valJ[jj] : 0.f;   // strict triu + valid
            float S1p = 0.f, S2p = 0.f, S1g = 0.f, S2g = 0.f;
            float isc = 0.f, icnt = 0.f;
#pragma unroll
            for (int t = 0; t < T; t++) {
                float4 a4 = *(const float4*)&sJ[t][jj][0];   // broadcast: 2 addrs/wave
                float4 b4 = *(const float4*)&sJ[t][jj][4];
                float dx = ipx[t] - a4.x, dy = ipy[t] - a4.y, dz = ipz[t] - a4.z;
                float d2p = fmaxf(fmaf(dx, dx, fmaf(dy, dy, dz * dz)), 1e-12f);
                float dp = __builtin_amdgcn_sqrtf(d2p);
                dx = igx[t] - a4.w; dy = igy[t] - b4.x; dz = igz[t] - b4.y;
                float d2g = fmaxf(fmaf(dx, dx, fmaf(dy, dy, dz * dz)), 1e-12f);
                float dg = __builtin_amdgcn_sqrtf(d2g);
                S1p = fmaf(fw[t], dp, S1p);  S2p = fmaf(fw[t], d2p, S2p);
                S1g = fmaf(fw[t], dg, S1g);  S2g = fmaf(fw[t], d2g, S2g);
                float diff = fabsf(dp - dg);
                float u = __expf(-diff);
                float Pn = fmaf(u, fmaf(u, fmaf(u, C_P3, C_P2), C_P1), C_P0);
                float Qd = fmaf(u, fmaf(u, fmaf(u, fmaf(u, C_E4, C_E3), C_E2), C_E1), 1.f);
                float s4 = u * Pn * __builtin_amdgcn_rcpf(Qd);
                float mk = (dg < 15.f) ? tg[t] : 0.f;       // dmask, predicated
                isc = fmaf(mk, s4, isc);
                icnt += mk;
            }
            score_sum = fmaf(w * 0.25f, isc, score_sum);
            cnt_sum = fmaf(w, icnt, cnt_sum);
            if (w > 0.f && rI == s_resJ[jj]) {
                // sum_t fw (d-m)^2 = S2 - S1^2 (2 - S0)
                float varp = fmaxf(fmaf(-S1p * S1p, 2.f - S0, S2p), 0.f);
                float varg = fmaxf(fmaf(-S1g * S1g, 2.f - S0, S2g), 0.f);
                float ds = __builtin_amdgcn_sqrtf(varp + 1e-8f)
                         - __builtin_amdgcn_sqrtf(varg + 1e-8f);
                int seg = bb * N_RES + rI;
                atomicAdd(ws + WS_FLEXS + seg, ds * ds);
                atomicAdd(ws + WS_FLEXC + seg, 1.f);
            }
        }
        float sc = block_reduce(score_sum, red);
        float ct = block_reduce(cnt_sum, red2);
        if (tid == 0) {
            atomicAdd(ws + WS_SCORE, 2.f * sc);   // i<j once; dmask symmetric
            atomicAdd(ws + WS_PAIRS, 2.f * ct);
        }
    } else if (blk < PAIR_BLOCKS + BOND_BLOCKS) {
        // ---------------- bond loss ----------------
        int gid = (blk - PAIR_BLOCKS) * 256 + tid;   // < B*T*NB exactly
        int bb = gid / (T * NB);
        int r  = gid % (T * NB);
        int t = r / NB, k = r % NB;
        float w = ((cond[bb * T + t] == 0) && bmask[bb * NB + k]) ? 1.f : 0.f;
        int i = bidx[(bb * NB + k) * 2 + 0];
        int j = bidx[(bb * NB + k) * 2 + 1];
        const float* base = xp + (size_t)(bb * T + t) * M * 3;
        float dx = base[i * 3 + 0] - base[j * 3 + 0];
        float dy = base[i * 3 + 1] - base[j * 3 + 1];
        float dz = base[i * 3 + 2] - base[j * 3 + 2];
        float len = __builtin_amdgcn_sqrtf(fmaf(dx, dx, fmaf(dy, dy, dz * dz)) + 1e-12f);
        float d = len - blen[bb * NB + k];
        float n  = block_reduce(w * d * d, red);
        float dn = block_reduce(w, red2);
        if (tid == 0) {
            atomicAdd(ws + WS_BONDN, n);
            atomicAdd(ws + WS_BONDD, dn);
        }
    } else {
        // ---------------- structure loss ----------------
        int bt = blk - PAIR_BLOCKS - BOND_BLOCKS;    // 0..B*T-1
        int bb = bt / T, t = bt % T;
        const float* p = xp + (size_t)(bb * T + t) * M * 3;
        const float* g = xg + (size_t)(bb * T + t) * M * 3;
        float lw = 0.f, lv = 0.f;
        for (int m = tid; m < M; m += 256) {
            float v = (amask[bb * M + m] && omask[bb * M + m]) ? 1.f : 0.f;
            lv += v;
            int mt = mtype[bb * M + m];
            float mw = (mt == 0) ? 1.f : ((mt == 3) ? 10.f : 5.f);
            float dx = p[m * 3 + 0] - g[m * 3 + 0];
            float dy = p[m * 3 + 1] - g[m * 3 + 1];
            float dz = p[m * 3 + 2] - g[m * 3 + 2];
            lw += fmaf(dx, dx, fmaf(dy, dy, dz * dz)) * v * mw;
        }
        float tot = block_reduce(lw, red);
        float nv  = block_reduce(lv, red2);
        if (tid == 0) {
            float per_frame = tot / fmaxf(nv, 1.f);
            float s = sigma[bb * T + t];
            float targ = (cond[bb * T + t] == 0) ? 1.f : 0.f;
            float den = s * 16.0f + 1e-8f;
            float edm = (s * s + 256.0f) / (den * den) * targ;
            atomicAdd(ws + WS_STRUCT, edm * per_frame);
        }
    }
}

// ---- final combine (separate dispatch = free device-wide sync) ----
__global__ void k_final(const float* __restrict__ ws, const int* __restrict__ cond,
                        float* __restrict__ out) {
    __shared__ float red[8], red2[8];
    int tid = threadIdx.x;
    float ls = 0.f, ln = 0.f;
    for (int seg = tid; seg < B * N_RES; seg += 256) {
        float c = ws[WS_FLEXC + seg];
        if (c > 0.f) { ls += ws[WS_FLEXS + seg] / c; ln += 1.f; }
    }
    float ssum = block_reduce(ls, red);
    float nsum = block_reduce(ln, red2);
    if (tid == 0) {
        float tc = 0.f;
        for (int i = 0; i < B * T; i++) tc += (cond[i] == 0) ? 1.f : 0.f;
        float l_struct = ws[WS_STRUCT] / fmaxf(tc, 1.f);
        float l_bond = ws[WS_BONDN] / fmaxf(ws[WS_BONDD], 1.f);
        float l_lddt = 1.f - ws[WS_SCORE] / fmaxf(ws[WS_PAIRS], 1.f);
        float l_local = ssum / fmaxf(nsum, 1.f);
        out[0] = l_struct + l_bond + l_lddt + 4.0f * l_local;
    }
}

extern "C" void kernel_launch(void* const* d_in, const int* in_sizes, int n_in,
                              void* d_out, int out_size, void* d_ws, size_t ws_size,
                              hipStream_t stream) {
    const float* xp    = (const float*)d_in[0];   // (B,T,M,3)
    const float* xg    = (const float*)d_in[1];   // (B,T,M,3)
    const float* sigma = (const float*)d_in[2];   // (B,T)
    const float* blen  = (const float*)d_in[3];   // (B,NB)
    const int*   cond  = (const int*)d_in[4];     // (B,T) bool->int32
    const int*   amask = (const int*)d_in[5];     // (B,M)
    const int*   omask = (const int*)d_in[6];     // (B,M)
    const int*   mtype = (const int*)d_in[7];     // (B,M)
    const int*   resid = (const int*)d_in[8];     // (B,M)
    const int*   bidx  = (const int*)d_in[9];     // (B,NB,2)
    const int*   bmask = (const int*)d_in[10];    // (B,NB)
    float* out = (float*)d_out;
    float* ws  = (float*)d_ws;

    hipMemsetAsync(ws, 0, WS_TOTAL * sizeof(float), stream);
    k_main<<<NBLK, 256, 0, stream>>>(xp, xg, sigma, blen, cond, amask, omask,
                                     mtype, resid, bidx, bmask, ws);
    k_final<<<1, 256, 0, stream>>>(ws, cond, out);
}

// Round 4
// 93.404 us; speedup vs baseline: 1.8523x; 1.2616x over previous
//
#include <hip/hip_runtime.h>
#include <math.h>

// Problem dims fixed by setup_inputs()
#define B 2
#define T 8
#define M 1024
#define NB 2048
#define N_RES 128
#define TILE 32
#define NTILES (M / TILE)                      // 32
#define NTPAIRS (NTILES * (NTILES + 1) / 2)    // 528
#define PAIR_BLOCKS (B * NTPAIRS)              // 1056
#define BOND_BLOCKS ((B * T * NB) / 256)       // 128
#define STRUCT_BLOCKS (B * T)                  // 16
#define NBLK (PAIR_BLOCKS + BOND_BLOCKS + STRUCT_BLOCKS)  // 1200

// workspace float offsets — per-block slots, NO same-address global atomics
#define WS_FLEXS  0                            // B*N_RES = 256 (atomic, sparse)
#define WS_FLEXC  256                          // 256     (atomic, sparse)
#define WS_SC     512                          // PAIR_BLOCKS
#define WS_CT     (512 + PAIR_BLOCKS)          // PAIR_BLOCKS
#define WS_BN     (512 + 2 * PAIR_BLOCKS)              // BOND_BLOCKS
#define WS_BD     (512 + 2 * PAIR_BLOCKS + BOND_BLOCKS)
#define WS_ST     (512 + 2 * PAIR_BLOCKS + 2 * BOND_BLOCKS)  // STRUCT_BLOCKS
#define WS_TOTAL  (512 + 2 * PAIR_BLOCKS + 2 * BOND_BLOCKS + STRUCT_BLOCKS)

// rational sigmoid-sum: sum_k sigmoid(th_k - diff) = u*Q'(u)/Q(u), u=e^{-diff},
// Q = prod_k (1 + c_k u), c_k = e^{th_k}, th = {0.5, 1, 2, 4}.
#define C_E1 66.35420923125896f
#define C_E2 678.6088038500627f
#define C_E3 2039.5821756957330f
#define C_E4 1808.0424144560632f
#define C_P0 C_E1
#define C_P1 1357.2176077001254f
#define C_P2 6118.7465270871990f
#define C_P3 7232.1696578242530f

__device__ inline float block_reduce(float v, float* smem) {
    int lane = threadIdx.x & 63, wid = threadIdx.x >> 6;
#pragma unroll
    for (int off = 32; off > 0; off >>= 1) v += __shfl_down(v, off, 64);
    __syncthreads();
    if (lane == 0) smem[wid] = v;
    __syncthreads();
    float r = 0.f;
    if (threadIdx.x == 0) {
        for (int i = 0; i < 4; i++) r += smem[i];
    }
    return r;   // valid on thread 0 only
}

// main kernel: pair blocks [0,1056), bond [1056,1184), struct [1184,1200).
__global__ __launch_bounds__(256) void k_main(
        const float* __restrict__ xp, const float* __restrict__ xg,
        const float* __restrict__ sigma, const float* __restrict__ blen,
        const int* __restrict__ cond, const int* __restrict__ amask,
        const int* __restrict__ omask, const int* __restrict__ mtype,
        const int* __restrict__ resid, const int* __restrict__ bidx,
        const int* __restrict__ bmask, float* __restrict__ ws) {
    __shared__ float red[8], red2[8];
    __shared__ float sI[T][TILE][6];     // stride-6: 2-way bank alias (free)
    __shared__ float sJ[T][TILE][8];     // stride-8: read as broadcast float4
    __shared__ float s_valJ[TILE];
    __shared__ int   s_resJ[TILE];
    __shared__ float fS[64], fC[64];     // per-block flex accumulation by residue&63

    const int tid = threadIdx.x;
    const int blk = blockIdx.x;

    if (blk < PAIR_BLOCKS) {
        // ---------------- fused lDDT + flexibility over pair tiles ----------------
        int bb = blk / NTPAIRS;
        int p  = blk % NTPAIRS;
        int ti = 0, rem = p;
        while (rem >= NTILES - ti) { rem -= NTILES - ti; ti++; }
        int tj = ti + rem;

        // frame weights from cond (uniform scalar work)
        float fw[T], tg[T];
        float cb = 0.f;
#pragma unroll
        for (int t = 0; t < T; t++) {
            tg[t] = (cond[bb * T + t] == 0) ? 1.f : 0.f;
            cb += tg[t];
        }
        float inv = 1.f / fmaxf(cb, 1.f);
        float S0 = cb * inv;
#pragma unroll
        for (int t = 0; t < T; t++) fw[t] = tg[t] * inv;

        // stage both tiles: thread -> (t, a)
        {
            int t = tid >> 5, a = tid & 31;
            size_t base = ((size_t)(bb * T + t)) * M * 3;
            const float* P = xp + base;
            const float* G = xg + base;
            int ia = (ti * TILE + a) * 3, ja = (tj * TILE + a) * 3;
            sI[t][a][0] = P[ia + 0]; sI[t][a][1] = P[ia + 1]; sI[t][a][2] = P[ia + 2];
            sI[t][a][3] = G[ia + 0]; sI[t][a][4] = G[ia + 1]; sI[t][a][5] = G[ia + 2];
            sJ[t][a][0] = P[ja + 0]; sJ[t][a][1] = P[ja + 1]; sJ[t][a][2] = P[ja + 2];
            sJ[t][a][3] = G[ja + 0]; sJ[t][a][4] = G[ja + 1]; sJ[t][a][5] = G[ja + 2];
        }
        if (tid < TILE) {
            int j = tj * TILE + tid;
            s_valJ[tid] = (amask[bb * M + j] && omask[bb * M + j]) ? 1.f : 0.f;
            s_resJ[tid] = resid[bb * M + j];
        }
        if (tid < 64) { fS[tid] = 0.f; fC[tid] = 0.f; }
        __syncthreads();

        // i-side coords into registers
        const int ii = tid & 31;
        float ipx[T], ipy[T], ipz[T], igx[T], igy[T], igz[T];
#pragma unroll
        for (int t = 0; t < T; t++) {
            ipx[t] = sI[t][ii][0]; ipy[t] = sI[t][ii][1]; ipz[t] = sI[t][ii][2];
            igx[t] = sI[t][ii][3]; igy[t] = sI[t][ii][4]; igz[t] = sI[t][ii][5];
        }
        const int   gi = ti * TILE + ii;
        const float vI = (amask[bb * M + gi] && omask[bb * M + gi]) ? 1.f : 0.f;
        const int   rI = resid[bb * M + gi];
        const int jbase = (tid >> 5) * 4;

        float score_sum = 0.f, cnt_sum = 0.f;
#pragma unroll
        for (int l = 0; l < 4; l++) {
            int jj = jbase + l;
            int gj = tj * TILE + jj;
            float w = (gi < gj) ? vI * s_valJ[jj] : 0.f;   // strict triu + valid
            float S1p = 0.f, S2p = 0.f, S1g = 0.f, S2g = 0.f;
            float isc = 0.f, icnt = 0.f;
#pragma unroll
            for (int t = 0; t < T; t++) {
                float4 a4 = *(const float4*)&sJ[t][jj][0];   // broadcast
                float4 b4 = *(const float4*)&sJ[t][jj][4];
                float dx = ipx[t] - a4.x, dy = ipy[t] - a4.y, dz = ipz[t] - a4.z;
                float d2p = fmaxf(fmaf(dx, dx, fmaf(dy, dy, dz * dz)), 1e-12f);
                float dp = __builtin_amdgcn_sqrtf(d2p);
                dx = igx[t] - a4.w; dy = igy[t] - b4.x; dz = igz[t] - b4.y;
                float d2g = fmaxf(fmaf(dx, dx, fmaf(dy, dy, dz * dz)), 1e-12f);
                float dg = __builtin_amdgcn_sqrtf(d2g);
                S1p = fmaf(fw[t], dp, S1p);  S2p = fmaf(fw[t], d2p, S2p);
                S1g = fmaf(fw[t], dg, S1g);  S2g = fmaf(fw[t], d2g, S2g);
                float diff = fabsf(dp - dg);
                float u = __expf(-diff);
                float Pn = fmaf(u, fmaf(u, fmaf(u, C_P3, C_P2), C_P1), C_P0);
                float Qd = fmaf(u, fmaf(u, fmaf(u, fmaf(u, C_E4, C_E3), C_E2), C_E1), 1.f);
                float s4 = u * Pn * __builtin_amdgcn_rcpf(Qd);
                float mk = (dg < 15.f) ? tg[t] : 0.f;       // dmask, predicated
                isc = fmaf(mk, s4, isc);
                icnt += mk;
            }
            score_sum = fmaf(w * 0.25f, isc, score_sum);
            cnt_sum = fmaf(w, icnt, cnt_sum);
            if (w > 0.f && rI == s_resJ[jj]) {
                // sum_t fw (d-m)^2 = S2 - S1^2 (2 - S0)
                float varp = fmaxf(fmaf(-S1p * S1p, 2.f - S0, S2p), 0.f);
                float varg = fmaxf(fmaf(-S1g * S1g, 2.f - S0, S2g), 0.f);
                float ds = __builtin_amdgcn_sqrtf(varp + 1e-8f)
                         - __builtin_amdgcn_sqrtf(varg + 1e-8f);
                atomicAdd(&fS[rI & 63], ds * ds);   // LDS atomic, block-local
                atomicAdd(&fC[rI & 63], 1.f);
            }
        }
        float sc = block_reduce(score_sum, red);
        float ct = block_reduce(cnt_sum, red2);
        if (tid == 0) {
            ws[WS_SC + blk] = 2.f * sc;   // plain store, summed in k_final
            ws[WS_CT + blk] = 2.f * ct;
        }
        __syncthreads();
        if (tid < 64) {
            float c = fC[tid];
            if (c > 0.f) {   // only ~5 residues per near-diagonal block
                // recover residue id: block residues span <64 consecutive ids
                int base = resid[bb * M + ti * TILE];   // min residue in tile i
                int r = (base & ~63) | tid;
                if (r < base) r += 64;
                atomicAdd(ws + WS_FLEXS + bb * N_RES + r, fS[tid]);
                atomicAdd(ws + WS_FLEXC + bb * N_RES + r, c);
            }
        }
    } else if (blk < PAIR_BLOCKS + BOND_BLOCKS) {
        // ---------------- bond loss ----------------
        int bix = blk - PAIR_BLOCKS;
        int gid = bix * 256 + tid;                   // < B*T*NB exactly
        int bb = gid / (T * NB);
        int r  = gid % (T * NB);
        int t = r / NB, k = r % NB;
        float w = ((cond[bb * T + t] == 0) && bmask[bb * NB + k]) ? 1.f : 0.f;
        int i = bidx[(bb * NB + k) * 2 + 0];
        int j = bidx[(bb * NB + k) * 2 + 1];
        const float* base = xp + (size_t)(bb * T + t) * M * 3;
        float dx = base[i * 3 + 0] - base[j * 3 + 0];
        float dy = base[i * 3 + 1] - base[j * 3 + 1];
        float dz = base[i * 3 + 2] - base[j * 3 + 2];
        float len = __builtin_amdgcn_sqrtf(fmaf(dx, dx, fmaf(dy, dy, dz * dz)) + 1e-12f);
        float d = len - blen[bb * NB + k];
        float n  = block_reduce(w * d * d, red);
        float dn = block_reduce(w, red2);
        if (tid == 0) {
            ws[WS_BN + bix] = n;
            ws[WS_BD + bix] = dn;
        }
    } else {
        // ---------------- structure loss ----------------
        int bt = blk - PAIR_BLOCKS - BOND_BLOCKS;    // 0..B*T-1
        int bb = bt / T, t = bt % T;
        const float* p = xp + (size_t)(bb * T + t) * M * 3;
        const float* g = xg + (size_t)(bb * T + t) * M * 3;
        float lw = 0.f, lv = 0.f;
        for (int m = tid; m < M; m += 256) {
            float v = (amask[bb * M + m] && omask[bb * M + m]) ? 1.f : 0.f;
            lv += v;
            int mt = mtype[bb * M + m];
            float mw = (mt == 0) ? 1.f : ((mt == 3) ? 10.f : 5.f);
            float dx = p[m * 3 + 0] - g[m * 3 + 0];
            float dy = p[m * 3 + 1] - g[m * 3 + 1];
            float dz = p[m * 3 + 2] - g[m * 3 + 2];
            lw += fmaf(dx, dx, fmaf(dy, dy, dz * dz)) * v * mw;
        }
        float tot = block_reduce(lw, red);
        float nv  = block_reduce(lv, red2);
        if (tid == 0) {
            float per_frame = tot / fmaxf(nv, 1.f);
            float s = sigma[bb * T + t];
            float targ = (cond[bb * T + t] == 0) ? 1.f : 0.f;
            float den = s * 16.0f + 1e-8f;
            float edm = (s * s + 256.0f) / (den * den) * targ;
            ws[WS_ST + bt] = edm * per_frame;
        }
    }
}

// ---- final combine (separate dispatch = free device-wide sync) ----
__global__ void k_final(const float* __restrict__ ws, const int* __restrict__ cond,
                        float* __restrict__ out) {
    __shared__ float red[8], red2[8];
    int tid = threadIdx.x;
    float sc = 0.f, ct = 0.f;
    for (int i = tid; i < PAIR_BLOCKS; i += 256) {
        sc += ws[WS_SC + i];
        ct += ws[WS_CT + i];
    }
    float bn = 0.f, bd = 0.f;
    for (int i = tid; i < BOND_BLOCKS; i += 256) {
        bn += ws[WS_BN + i];
        bd += ws[WS_BD + i];
    }
    float st = (tid < STRUCT_BLOCKS) ? ws[WS_ST + tid] : 0.f;
    float ls = 0.f, ln = 0.f;
    for (int seg = tid; seg < B * N_RES; seg += 256) {
        float c = ws[WS_FLEXC + seg];
        if (c > 0.f) { ls += ws[WS_FLEXS + seg] / c; ln += 1.f; }
    }
    float scs = block_reduce(sc, red);
    float cts = block_reduce(ct, red2);
    float bns = block_reduce(bn, red);
    float bds = block_reduce(bd, red2);
    float sts = block_reduce(st, red);
    float lss = block_reduce(ls, red2);
    float lns = block_reduce(ln, red);
    if (tid == 0) {
        float tc = 0.f;
        for (int i = 0; i < B * T; i++) tc += (cond[i] == 0) ? 1.f : 0.f;
        float l_struct = sts / fmaxf(tc, 1.f);
        float l_bond = bns / fmaxf(bds, 1.f);
        float l_lddt = 1.f - scs / fmaxf(cts, 1.f);
        float l_local = lss / fmaxf(lns, 1.f);
        out[0] = l_struct + l_bond + l_lddt + 4.0f * l_local;
    }
}

extern "C" void kernel_launch(void* const* d_in, const int* in_sizes, int n_in,
                              void* d_out, int out_size, void* d_ws, size_t ws_size,
                              hipStream_t stream) {
    const float* xp    = (const float*)d_in[0];   // (B,T,M,3)
    const float* xg    = (const float*)d_in[1];   // (B,T,M,3)
    const float* sigma = (const float*)d_in[2];   // (B,T)
    const float* blen  = (const float*)d_in[3];   // (B,NB)
    const int*   cond  = (const int*)d_in[4];     // (B,T) bool->int32
    const int*   amask = (const int*)d_in[5];     // (B,M)
    const int*   omask = (const int*)d_in[6];     // (B,M)
    const int*   mtype = (const int*)d_in[7];     // (B,M)
    const int*   resid = (const int*)d_in[8];     // (B,M)
    const int*   bidx  = (const int*)d_in[9];     // (B,NB,2)
    const int*   bmask = (const int*)d_in[10];    // (B,NB)
    float* out = (float*)d_out;
    float* ws  = (float*)d_ws;

    // only the flex (atomic) region needs zeroing; block slots are written
    // unconditionally by their owning blocks
    hipMemsetAsync(ws, 0, 512 * sizeof(float), stream);
    k_main<<<NBLK, 256, 0, stream>>>(xp, xg, sigma, blen, cond, amask, omask,
                                     mtype, resid, bidx, bmask, ws);
    k_final<<<1, 256, 0, stream>>>(ws, cond, out);
}